// Round 12
// baseline (121.007 us; speedup 1.0000x reference)
//
#include <hip/hip_runtime.h>
#include <hip/hip_bf16.h>
#include <math.h>

// Problem constants
#define TT       16      // sequence length T
#define NSEQ     256     // B*H*W sequences
#define TOK      4096    // NSEQ * TT tokens
#define DMODEL   512
#define DINNER   1024
#define DSTATE   64
#define NHEADS   16
#define HEADDIM  64
#define CONVDIM  1152    // D_INNER + 2*D_STATE
#define DINPROJ  2192    // full in_proj rows
#define DTOFF    2176    // start of dt rows in in_proj
#define ZLD      2176    // zb row stride (z:0..1023, xBC:1024..2175)
#define NPAD_IP  2304    // in_proj rows padded to multiple of 128

using bf16x8 = __attribute__((ext_vector_type(8))) short;
using f32x4  = __attribute__((ext_vector_type(4))) float;
typedef __hip_bfloat16 bf16;

__device__ __forceinline__ void gload_lds16(const void* g, void* l) {
    __builtin_amdgcn_global_load_lds(
        (const __attribute__((address_space(1))) unsigned int*)g,
        (__attribute__((address_space(3))) unsigned int*)l,
        16, 0, 0);
}

// ---------------------------------------------------------------------------
// MFMA bf16 GEMM: C[M][N] = A[M][K] * B[N][K]^T, with epilogue options.
// 128 x (NFRAG*32) tile, BK=32, 256 threads (4 waves, 2x2 wave grid).
// BIAS: 0 none, 1 per-col, 2 per-row. OUTBF: bf16 out to Ch (else fp32 Cf).
// DUAL: additionally store fp32 to C2.
// PARTSCALE: row scale = rsqrt(mean part[row][0..3] + eps).
// COLSCALE:  col scale = rsqrt(mean part[col][0..3] + eps), applied pre-bias.
// ---------------------------------------------------------------------------
template<int NFRAG, bool OUTBF, bool DUAL, int BIAS, bool PARTSCALE, bool COLSCALE>
__global__ __launch_bounds__(256) void mfma_gemm(
    const bf16* __restrict__ A, const bf16* __restrict__ B,
    const float* __restrict__ bias, const float* __restrict__ rs,
    float* __restrict__ Cf, bf16* __restrict__ Ch, float* __restrict__ C2,
    int Nreal, int K, int lda, int ldb, int ldc)
{
    constexpr int BN = NFRAG * 32;
    __shared__ short As[128 * 32];
    __shared__ short Bs[BN * 32];

    const int tid = threadIdx.x;
    const int wv = tid >> 6, ln = tid & 63;
    const int m0 = blockIdx.x * 128, n0 = blockIdx.y * BN;
    const int wr = wv >> 1, wc = wv & 1;        // 2x2 wave grid
    const int lr = ln & 15, lk = (ln >> 4) * 8; // fragment row / k-offset

    f32x4 acc[4][NFRAG];
#pragma unroll
    for (int m = 0; m < 4; ++m)
#pragma unroll
        for (int n = 0; n < NFRAG; ++n) acc[m][n] = (f32x4){0.f, 0.f, 0.f, 0.f};

    for (int k0 = 0; k0 < K; k0 += 32) {
        __syncthreads();   // previous iteration's reads done
#pragma unroll
        for (int r = 0; r < 2; ++r) {
            const int ofs = r * 4096 + tid * 16;    // byte in 8KB A tile
            const int row = ofs >> 6;               // 64 B per row
            const int ke  = (ofs & 63) >> 1;        // element in row
            gload_lds16(A + (size_t)(m0 + row) * lda + k0 + ke, (char*)As + ofs);
        }
#pragma unroll
        for (int r = 0; r < NFRAG / 2; ++r) {
            const int ofs = r * 4096 + tid * 16;
            const int row = ofs >> 6;
            const int ke  = (ofs & 63) >> 1;
            gload_lds16(B + (size_t)(n0 + row) * ldb + k0 + ke, (char*)Bs + ofs);
        }
        __syncthreads();   // staging complete

        bf16x8 af[4], bfr[NFRAG];
#pragma unroll
        for (int m = 0; m < 4; ++m)
            af[m] = *(const bf16x8*)&As[(wr * 64 + m * 16 + lr) * 32 + lk];
#pragma unroll
        for (int n = 0; n < NFRAG; ++n)
            bfr[n] = *(const bf16x8*)&Bs[(wc * (BN / 2) + n * 16 + lr) * 32 + lk];
#pragma unroll
        for (int m = 0; m < 4; ++m)
#pragma unroll
            for (int n = 0; n < NFRAG; ++n)
                acc[m][n] = __builtin_amdgcn_mfma_f32_16x16x32_bf16(
                    af[m], bfr[n], acc[m][n], 0, 0, 0);
    }

    // epilogue: C/D mapping col = lane&15, row = (lane>>4)*4 + reg
    const int mBase = m0 + wr * 64, nBase = n0 + wc * (BN / 2);

    float scn[NFRAG], cbv[NFRAG];
#pragma unroll
    for (int n = 0; n < NFRAG; ++n) {
        const int col = nBase + n * 16 + lr;
        scn[n] = 1.f; cbv[n] = 0.f;
        if (col < Nreal) {
            if (COLSCALE) {
                const float4 pv = *(const float4*)(rs + (size_t)col * 4);
                scn[n] = rsqrtf((pv.x + pv.y + pv.z + pv.w) * (1.f / 1024.f) + 1e-5f);
            }
            if (BIAS == 1) cbv[n] = bias[col];
        }
    }

#pragma unroll
    for (int m = 0; m < 4; ++m) {
#pragma unroll
        for (int j = 0; j < 4; ++j) {
            const int row = mBase + m * 16 + (ln >> 4) * 4 + j;
            float sc = 1.f, rb = 0.f;
            if (PARTSCALE) {
                const float4 pv = *(const float4*)(rs + (size_t)row * 4);
                sc = rsqrtf((pv.x + pv.y + pv.z + pv.w) * (1.f / 1024.f) + 1e-5f);
            }
            if (BIAS == 2) rb = bias[row];
#pragma unroll
            for (int n = 0; n < NFRAG; ++n) {
                const int col = nBase + n * 16 + lr;
                if (col < Nreal) {
                    float v = acc[m][n][j];
                    if (PARTSCALE) v *= sc;
                    if (COLSCALE)  v *= scn[n];
                    v += cbv[n] + rb;
                    if (OUTBF) {
                        Ch[(size_t)row * ldc + col] = __float2bfloat16(v);
                        if (DUAL) C2[(size_t)row * ldc + col] = v;
                    } else {
                        Cf[(size_t)row * ldc + col] = v;
                    }
                }
            }
        }
    }
}

// ---------------------------------------------------------------------------
// Merged prep:
//  [0,128):      Wc[h][c] = sum_d ip[DTOFF+h][d]*pi[d][c] (fp32; waves split d)
//                + bc[h] = sum_d pib[d]*ip[DTOFF+h][d]     (on c0==0 blocks)
//  [128,896):    weights -> bf16: wpi, wpo, wip (pad)      grid-stride
//  [896,1408):   wopT[d][o] = bf16(op[o][d] * nw[d])       32x32 tiles
//  [1408,3456):  hsT[v][c] = bf16(hs[c][v])                32x32 tiles
// ---------------------------------------------------------------------------
#define SZ_PI  (512 * 512)
#define SZ_PO  (512 * 512)
#define SZ_IP  (DINPROJ * 512)
#define SZ_IPP (NPAD_IP * 512)
#define SZ_ALL (SZ_PI + SZ_PO + SZ_IPP)
#define NB_WC  128
#define NB_WB  768
#define NB_WT  512
#define NB_HT  2048
#define NB_ALL (NB_WC + NB_WB + NB_WT + NB_HT)

__global__ __launch_bounds__(256) void prep_all(
    const float* __restrict__ pi, const float* __restrict__ po,
    const float* __restrict__ op, const float* __restrict__ ip,
    const float* __restrict__ nw, const float* __restrict__ pib,
    const float* __restrict__ hs,
    bf16* __restrict__ wpi, bf16* __restrict__ wpo, bf16* __restrict__ wip,
    bf16* __restrict__ wopT, bf16* __restrict__ hsT,
    float* __restrict__ Wc, float* __restrict__ bc)
{
    __shared__ float smem[32 * 33];
    const int b = blockIdx.x, tid = threadIdx.x;

    if (b < NB_WC) {
        // Wc: block b -> head h = b>>3, c-chunk (b&7)*64. Waves split d.
        const int h = b >> 3, c0 = (b & 7) * 64;
        const int w = tid >> 6, l = tid & 63;
        const float* wdt = ip + (size_t)(DTOFF + h) * DMODEL;
        float acc = 0.f;
#pragma unroll 8
        for (int i = 0; i < 128; ++i) {
            const int d = w * 128 + i;
            acc = fmaf(wdt[d], pi[(size_t)d * DMODEL + c0 + l], acc);
        }
        smem[w * 64 + l] = acc;
        __syncthreads();
        if (tid < 64)
            Wc[(size_t)h * DMODEL + c0 + tid] =
                smem[tid] + smem[64 + tid] + smem[128 + tid] + smem[192 + tid];
        if ((b & 7) == 0) {
            // bc[h] = pib . wdt
            float p = pib[tid] * wdt[tid] + pib[tid + 256] * wdt[tid + 256];
#pragma unroll
            for (int off = 32; off >= 1; off >>= 1) p += __shfl_xor(p, off);
            if ((tid & 63) == 0) smem[300 + (tid >> 6)] = p;
            __syncthreads();
            if (tid == 0)
                bc[h] = smem[300] + smem[301] + smem[302] + smem[303];
        }
    } else if (b < NB_WC + NB_WB) {
        const int wb = b - NB_WC;
        for (int idx = wb * 256 + tid; idx < SZ_ALL; idx += NB_WB * 256) {
            if (idx < SZ_PI) {
                wpi[idx] = __float2bfloat16(pi[idx]);
            } else if (idx < SZ_PI + SZ_PO) {
                int j = idx - SZ_PI; wpo[j] = __float2bfloat16(po[j]);
            } else {
                int j = idx - SZ_PI - SZ_PO;
                wip[j] = (j < SZ_IP) ? __float2bfloat16(ip[j])
                                     : __float2bfloat16(0.f);
            }
        }
    } else if (b < NB_WC + NB_WB + NB_WT) {
        // wopT[d][o] = op[o][d] * nw[d]  (bf16); op is [512 o][1024 d]
        const int tb = b - NB_WC - NB_WB;
        const int o0 = (tb & 15) * 32, d0 = (tb >> 4) * 32;
        const int tx = tid & 31, ty = tid >> 5;   // 32 x 8
#pragma unroll
        for (int i = 0; i < 4; ++i)
            smem[(ty + 8 * i) * 33 + tx] =
                op[(size_t)(o0 + ty + 8 * i) * DINNER + d0 + tx];
        __syncthreads();
#pragma unroll
        for (int i = 0; i < 4; ++i) {
            const int d = d0 + ty + 8 * i;
            wopT[(size_t)d * DMODEL + o0 + tx] =
                __float2bfloat16(smem[tx * 33 + ty + 8 * i] * nw[d]);
        }
    } else {
        // hsT[v][c] = hs[c][v] (bf16)
        const int tb = b - NB_WC - NB_WB - NB_WT;
        const int v0 = (tb & 127) * 32, c0 = (tb >> 7) * 32;
        const int tx = tid & 31, ty = tid >> 5;   // 32 x 8
#pragma unroll
        for (int i = 0; i < 4; ++i)
            smem[(ty + 8 * i) * 33 + tx] =
                hs[(size_t)(c0 + ty + 8 * i) * TOK + v0 + tx];
        __syncthreads();
#pragma unroll
        for (int i = 0; i < 4; ++i)
            hsT[(size_t)(v0 + ty + 8 * i) * DMODEL + c0 + tx] =
                __float2bfloat16(smem[tx * 33 + ty + 8 * i]);
    }
}

// ---------------------------------------------------------------------------
// dtf[v][h] = sum_c hsT_bf16[v][c] * Wc[h][c] + bc[h]   (fp32 accumulate).
// One bf16 rounding (hs) vs two on the old xv32 path -> slightly MORE exact.
// One block per token v (proven dt_fix shape); 4 waves x 4 heads; lane = 8 c.
// ---------------------------------------------------------------------------
__global__ __launch_bounds__(256) void dt_bf_kernel(
    const bf16* __restrict__ hsT, const float* __restrict__ Wc,
    const float* __restrict__ bc, float* __restrict__ dtf)
{
    const int v = blockIdx.x;
    const int w = threadIdx.x >> 6, l = threadIdx.x & 63;

    const bf16x8 hv = *(const bf16x8*)(hsT + (size_t)v * DMODEL + l * 8);
    float hf[8];
#pragma unroll
    for (int j = 0; j < 8; ++j) {
        const unsigned int bits = ((unsigned int)(unsigned short)hv[j]) << 16;
        hf[j] = __uint_as_float(bits);
    }
#pragma unroll
    for (int hh = 0; hh < 4; ++hh) {
        const int h = w * 4 + hh;
        const float4* wr = (const float4*)(Wc + (size_t)h * DMODEL);
        const float4 w0 = wr[l * 2], w1 = wr[l * 2 + 1];
        float dot = hf[0] * w0.x + hf[1] * w0.y + hf[2] * w0.z + hf[3] * w0.w
                  + hf[4] * w1.x + hf[5] * w1.y + hf[6] * w1.z + hf[7] * w1.w;
#pragma unroll
        for (int off = 32; off >= 1; off >>= 1) dot += __shfl_xor(dot, off);
        if (l == 0) dtf[(size_t)v * 16 + h] = dot + bc[h];
    }
}

// ---------------------------------------------------------------------------
// Fused conv + SSD + D-skip + z-gating; emits unnormalized g (bf16) and
// per-(token, head-quad) partial sum-of-squares.
// Grid (n, hq): 256 x 4 blocks, 256 threads = 4 waves; wave w = head hq*4+w.
// SSD (exact for T=16):
//   y_t[p] = sum_{s<=t} exp(a*(cum_t - cum_s)) * (C_t . B_s) * dt_s * x_s[p]
// ---------------------------------------------------------------------------
__global__ __launch_bounds__(256) void ssd_kernel(
    const bf16* __restrict__ zb, const float* __restrict__ dtf,
    const float* __restrict__ conv_w, const float* __restrict__ conv_b,
    const float* __restrict__ dt_bias, const float* __restrict__ A_log,
    const float* __restrict__ Dp,
    bf16* __restrict__ gb, float* __restrict__ part)
{
    const int n = blockIdx.x, hq = blockIdx.y;
    const int tid = threadIdx.x;
    const int w = tid >> 6, p = tid & 63;
    const int h = hq * 4 + w;
    const int ch = hq * 256 + tid;          // x / z / g channel

    __shared__ float Bsh[16][68];           // [t][state]
    __shared__ float Csh[16][68];
    __shared__ float Gsh[16][16];           // [t][s] = C_t . B_s
    __shared__ float Msh[4][256];           // per-wave mask [t*16+s]
    __shared__ float red4[16][4];           // [t][wave] partial sumsq

    // ---- phase 0: load x-part (bf16) for own channel, all 16 t ----
    float ld[16];
#pragma unroll
    for (int t = 0; t < 16; ++t)
        ld[t] = __bfloat162float(zb[(size_t)(t * 256 + n) * ZLD + 1024 + ch]);

    const float cw0 = conv_w[ch * 4 + 0], cw1 = conv_w[ch * 4 + 1],
                cw2 = conv_w[ch * 4 + 2], cw3 = conv_w[ch * 4 + 3];
    const float cb = conv_b[ch];
    float xs[16];
#pragma unroll
    for (int t = 0; t < 16; ++t) {
        float a = fmaf(ld[t], cw3, cb);
        if (t >= 1) a = fmaf(ld[t - 1], cw2, a);
        if (t >= 2) a = fmaf(ld[t - 2], cw1, a);
        if (t >= 3) a = fmaf(ld[t - 3], cw0, a);
        xs[t] = a / (1.f + __expf(-a));
    }

    // ---- conv B/C channels (cols 2048..2175) by threads 0..127 ----
    if (tid < 128) {
        const int cc = 1024 + tid;          // conv channel index
        const float dw0 = conv_w[cc * 4 + 0], dw1 = conv_w[cc * 4 + 1],
                    dw2 = conv_w[cc * 4 + 2], dw3 = conv_w[cc * 4 + 3];
        const float db = conv_b[cc];
        float q0 = 0.f, q1 = 0.f, q2 = 0.f;
#pragma unroll
        for (int t = 0; t < 16; ++t) {
            const float cur =
                __bfloat162float(zb[(size_t)(t * 256 + n) * ZLD + 2048 + tid]);
            float a = fmaf(cur, dw3, db);
            a = fmaf(q2, dw2, a);
            a = fmaf(q1, dw1, a);
            a = fmaf(q0, dw0, a);
            const float val = a / (1.f + __expf(-a));
            if (tid < 64) Bsh[t][tid] = val; else Csh[t][tid - 64] = val;
            q0 = q1; q1 = q2; q2 = cur;
        }
    }

    // ---- per-head dt (softplus, fp32) + inclusive cumsum over t ----
    const float a_h = -__expf(A_log[h]);
    float dtv_l = 0.f;
    if (p < 16) {
        const float raw = dtf[(size_t)(p * 256 + n) * 16 + h] + dt_bias[h];
        dtv_l = (raw > 20.f) ? raw : log1pf(__expf(raw));
    }
    float cum_l = dtv_l;
#pragma unroll
    for (int off = 1; off < 16; off <<= 1) {
        const float tmp = __shfl_up(cum_l, off);
        if (p >= off) cum_l += tmp;
    }
    __syncthreads();   // Bsh/Csh ready

    // ---- G[t][s] = C_t . B_s (head-independent) ----
    {
        const int t = tid >> 4, s = tid & 15;
        float acc = 0.f;
#pragma unroll
        for (int k = 0; k < 64; ++k)
            acc = fmaf(Csh[t][k], Bsh[s][k], acc);
        Gsh[t][s] = acc;
    }
    __syncthreads();

    // ---- per-head mask M[t][s] = exp(a*(cum_t-cum_s)) * G * dt_s ----
    float dtv_all[16], cum_all[16];
#pragma unroll
    for (int t = 0; t < 16; ++t) {
        dtv_all[t] = __shfl(dtv_l, t);
        cum_all[t] = __shfl(cum_l, t);
    }
#pragma unroll
    for (int q = 0; q < 4; ++q) {
        const int idx = p * 4 + q;
        const int t = idx >> 4, s = idx & 15;
        float m = 0.f;
        if (s <= t)
            m = __expf(a_h * (cum_all[t] - cum_all[s])) * Gsh[t][s] * dtv_all[s];
        Msh[w][idx] = m;   // wave-private; no barrier needed
    }

    // issue z loads; latency hides under phase 4 compute
    float zl[16];
#pragma unroll
    for (int t = 0; t < 16; ++t)
        zl[t] = __bfloat162float(zb[(size_t)(t * 256 + n) * ZLD + ch]);

    // ---- Y = M . x + D*x, gate with silu(z) ----
    const float Dh = Dp[h];
    float g[16];
#pragma unroll
    for (int t = 0; t < 16; ++t) {
        float y = 0.f;
#pragma unroll
        for (int s = 0; s <= t; ++s)
            y = fmaf(Msh[w][t * 16 + s], xs[s], y);
        y = fmaf(Dh, xs[t], y);
        g[t] = y * (zl[t] / (1.f + __expf(-zl[t])));
    }

    // ---- partial sum of squares per (t, wave) + write g ----
#pragma unroll
    for (int t = 0; t < 16; ++t) {
        float ss = g[t] * g[t];
#pragma unroll
        for (int off = 32; off >= 1; off >>= 1) ss += __shfl_xor(ss, off);
        if (p == 0) red4[t][w] = ss;
        gb[(size_t)(t * 256 + n) * DINNER + ch] = __float2bfloat16(g[t]);
    }
    __syncthreads();
    if (tid < 16)
        part[(size_t)(tid * 256 + n) * 4 + hq] =
            red4[tid][0] + red4[tid][1] + red4[tid][2] + red4[tid][3];
}

// ---------------------------------------------------------------------------
extern "C" void kernel_launch(void* const* d_in, const int* in_sizes, int n_in,
                              void* d_out, int out_size, void* d_ws, size_t ws_size,
                              hipStream_t stream) {
    const float* hs         = (const float*)d_in[0];   // (1,512,16,16,16)
    const float* proj_in_w  = (const float*)d_in[1];   // (512,512)
    const float* proj_in_b  = (const float*)d_in[2];   // (512)
    const float* proj_out_w = (const float*)d_in[3];   // (512,512)
    const float* proj_out_b = (const float*)d_in[4];   // (512)
    const float* in_proj_w  = (const float*)d_in[5];   // (2192,512)
    const float* conv_w     = (const float*)d_in[6];   // (1152,4)
    const float* conv_b     = (const float*)d_in[7];   // (1152)
    const float* dt_bias    = (const float*)d_in[8];   // (16)
    const float* A_log      = (const float*)d_in[9];   // (16)
    const float* Dp         = (const float*)d_in[10];  // (16)
    const float* norm_w     = (const float*)d_in[11];  // (1024)
    const float* out_proj_w = (const float*)d_in[12];  // (512,1024)
    float* out = (float*)d_out;

    // workspace layout (fp32 first, then bf16)
    float* ws      = (float*)d_ws;
    float* dtf     = ws;                                   // 4096*16 f32
    float* part    = dtf + (size_t)TOK * 16;               // 4096*4  f32
    float* Wc      = part + (size_t)TOK * 4;               // 16*512  f32
    float* bc      = Wc + 16 * DMODEL;                     // 16      f32
    bf16*  hsT     = (bf16*)(bc + 16);                     // 4096*512
    bf16*  xv_bf   = hsT + (size_t)TOK * DMODEL;           // 4096*512
    bf16*  zb      = xv_bf + (size_t)TOK * DMODEL;         // 4096*2176
    bf16*  gb      = zb + (size_t)TOK * ZLD;               // 4096*1024
    bf16*  wpi     = gb + (size_t)TOK * DINNER;            // 512*512
    bf16*  wpo     = wpi + SZ_PI;                          // 512*512
    bf16*  wip     = wpo + SZ_PO;                          // 2304*512
    bf16*  wopT    = wip + SZ_IPP;                         // 1024*512 (nw folded)
    bf16*  Wbig    = wopT + (size_t)DINNER * DMODEL;       // 512*1024

    // P0: Wc/bc (fp32), weights -> bf16, wopT (nw folded), hs -> hsT
    prep_all<<<NB_ALL, 256, 0, stream>>>(
        proj_in_w, proj_out_w, out_proj_w, in_proj_w, norm_w, proj_in_b, hs,
        wpi, wpo, wip, wopT, hsT, Wc, bc);

    // P2: Wbig[c][d] = sum_o wpo[c][o] * wopT[d][o]   (bf16, 512x1024x512)
    mfma_gemm<2, true, false, 0, false, false><<<dim3(4, 16), 256, 0, stream>>>(
        wpo, wopT, nullptr, nullptr, nullptr, Wbig, nullptr,
        DINNER, DMODEL, DMODEL, DMODEL, DINNER);

    // K1: xv[v][d] = hsT[v][:] . wpi[d][:] + b[d]   (bf16 out only)
    mfma_gemm<2, true, false, 1, false, false><<<dim3(32, 8), 256, 0, stream>>>(
        hsT, wpi, proj_in_b, nullptr, nullptr, xv_bf, nullptr,
        DMODEL, DMODEL, DMODEL, DMODEL, DMODEL);

    // K2: zb[v][e] = xv[v][:] . wip[e][:]   (bf16 out, cols 0..2175)
    mfma_gemm<4, true, false, 0, false, false><<<dim3(32, 18), 256, 0, stream>>>(
        xv_bf, wip, nullptr, nullptr, nullptr, zb, nullptr,
        ZLD, DMODEL, DMODEL, DMODEL, ZLD);

    // K2b: fp32 dt from hsT . Wc + bc  (single bf16 rounding on hs)
    dt_bf_kernel<<<TOK, 256, 0, stream>>>(hsT, Wc, bc, dtf);

    // K4: fused conv + SSD + gate -> gb (bf16) + partial sumsq
    ssd_kernel<<<dim3(NSEQ, 4), 256, 0, stream>>>(
        zb, dtf, conv_w, conv_b, dt_bias, A_log, Dp, gb, part);

    // K67: out[c][v] = scale[v] * (Wbig[c][:] . gb[v][:]) + pob[c]
    //      (fp32, row-major = out layout; COLSCALE + row bias)
    mfma_gemm<2, false, false, 2, false, true><<<dim3(4, 64), 256, 0, stream>>>(
        Wbig, gb, proj_out_b, part, out, nullptr, nullptr,
        TOK, DINNER, DINNER, DINNER, TOK);
}

// Round 13
// 100.427 us; speedup vs baseline: 1.2049x; 1.2049x over previous
//
#include <hip/hip_runtime.h>
#include <hip/hip_bf16.h>
#include <math.h>

// Problem constants
#define TT       16      // sequence length T
#define NSEQ     256     // B*H*W sequences
#define TOK      4096    // NSEQ * TT tokens
#define DMODEL   512
#define DINNER   1024
#define DSTATE   64
#define NHEADS   16
#define HEADDIM  64
#define CONVDIM  1152    // D_INNER + 2*D_STATE
#define DINPROJ  2192    // full in_proj rows
#define DTOFF    2176    // start of dt rows in in_proj
#define ZLD      2176    // zb row stride (z:0..1023, xBC:1024..2175)

using bf16x8 = __attribute__((ext_vector_type(8))) short;
using f32x4  = __attribute__((ext_vector_type(4))) float;
typedef __hip_bfloat16 bf16;

__device__ __forceinline__ void gload_lds16(const void* g, void* l) {
    __builtin_amdgcn_global_load_lds(
        (const __attribute__((address_space(1))) unsigned int*)g,
        (__attribute__((address_space(3))) unsigned int*)l,
        16, 0, 0);
}

// ---------------------------------------------------------------------------
// GEMM core (device fn): C[M][N] = A[M][K]*B[N][K]^T (+ bias[col]), bf16 out.
// Tile 128 x (NFRAG*32), BK=32, 256 threads (4 waves, 2x2 wave grid).
// ---------------------------------------------------------------------------
template<int NFRAG>
__device__ __forceinline__ void gemm_core(
    short* As, short* Bs,
    const bf16* __restrict__ A, const bf16* __restrict__ B,
    const float* __restrict__ bias, bf16* __restrict__ Ch,
    int bm, int bn, int K, int lda, int ldb, int ldc, int Nreal)
{
    constexpr int BN = NFRAG * 32;
    const int tid = threadIdx.x;
    const int wv = tid >> 6, ln = tid & 63;
    const int m0 = bm * 128, n0 = bn * BN;
    const int wr = wv >> 1, wc = wv & 1;
    const int lr = ln & 15, lk = (ln >> 4) * 8;

    f32x4 acc[4][NFRAG];
#pragma unroll
    for (int m = 0; m < 4; ++m)
#pragma unroll
        for (int n = 0; n < NFRAG; ++n) acc[m][n] = (f32x4){0.f, 0.f, 0.f, 0.f};

    for (int k0 = 0; k0 < K; k0 += 32) {
        __syncthreads();
#pragma unroll
        for (int r = 0; r < 2; ++r) {
            const int ofs = r * 4096 + tid * 16;
            const int row = ofs >> 6;
            const int ke  = (ofs & 63) >> 1;
            gload_lds16(A + (size_t)(m0 + row) * lda + k0 + ke, (char*)As + ofs);
        }
#pragma unroll
        for (int r = 0; r < NFRAG / 2; ++r) {
            const int ofs = r * 4096 + tid * 16;
            const int row = ofs >> 6;
            const int ke  = (ofs & 63) >> 1;
            gload_lds16(B + (size_t)(n0 + row) * ldb + k0 + ke, (char*)Bs + ofs);
        }
        __syncthreads();

        bf16x8 af[4], bfr[NFRAG];
#pragma unroll
        for (int m = 0; m < 4; ++m)
            af[m] = *(const bf16x8*)&As[(wr * 64 + m * 16 + lr) * 32 + lk];
#pragma unroll
        for (int n = 0; n < NFRAG; ++n)
            bfr[n] = *(const bf16x8*)&Bs[(wc * (BN / 2) + n * 16 + lr) * 32 + lk];
#pragma unroll
        for (int m = 0; m < 4; ++m)
#pragma unroll
            for (int n = 0; n < NFRAG; ++n)
                acc[m][n] = __builtin_amdgcn_mfma_f32_16x16x32_bf16(
                    af[m], bfr[n], acc[m][n], 0, 0, 0);
    }

    const int mBase = m0 + wr * 64, nBase = n0 + wc * (BN / 2);
    float cbv[NFRAG];
#pragma unroll
    for (int n = 0; n < NFRAG; ++n) {
        const int col = nBase + n * 16 + lr;
        cbv[n] = (bias != nullptr && col < Nreal) ? bias[col] : 0.f;
    }
#pragma unroll
    for (int m = 0; m < 4; ++m) {
#pragma unroll
        for (int j = 0; j < 4; ++j) {
            const int row = mBase + m * 16 + (ln >> 4) * 4 + j;
#pragma unroll
            for (int n = 0; n < NFRAG; ++n) {
                const int col = nBase + n * 16 + lr;
                if (col < Nreal)
                    Ch[(size_t)row * ldc + col] =
                        __float2bfloat16(acc[m][n][j] + cbv[n]);
            }
        }
    }
}

// ---------------------------------------------------------------------------
// Standalone MFMA GEMM for K67: fp32 out, per-row bias, per-col RMS scale.
// out[c][v] = rsqrt(mean part[v] + eps) * (A[c][:] . B[v][:]) + bias[c]
// ---------------------------------------------------------------------------
__global__ __launch_bounds__(256) void k67_gemm(
    const bf16* __restrict__ A, const bf16* __restrict__ B,
    const float* __restrict__ bias, const float* __restrict__ rs,
    float* __restrict__ Cf, int K, int lda, int ldb, int ldc)
{
    __shared__ short As[128 * 32];
    __shared__ short Bs[64 * 32];

    const int tid = threadIdx.x;
    const int wv = tid >> 6, ln = tid & 63;
    const int m0 = blockIdx.x * 128, n0 = blockIdx.y * 64;
    const int wr = wv >> 1, wc = wv & 1;
    const int lr = ln & 15, lk = (ln >> 4) * 8;

    f32x4 acc[4][2];
#pragma unroll
    for (int m = 0; m < 4; ++m)
#pragma unroll
        for (int n = 0; n < 2; ++n) acc[m][n] = (f32x4){0.f, 0.f, 0.f, 0.f};

    for (int k0 = 0; k0 < K; k0 += 32) {
        __syncthreads();
#pragma unroll
        for (int r = 0; r < 2; ++r) {
            const int ofs = r * 4096 + tid * 16;
            const int row = ofs >> 6;
            const int ke  = (ofs & 63) >> 1;
            gload_lds16(A + (size_t)(m0 + row) * lda + k0 + ke, (char*)As + ofs);
        }
        {
            const int ofs = tid * 16;
            const int row = ofs >> 6;
            const int ke  = (ofs & 63) >> 1;
            gload_lds16(B + (size_t)(n0 + row) * ldb + k0 + ke, (char*)Bs + ofs);
        }
        __syncthreads();

        bf16x8 af[4], bfr[2];
#pragma unroll
        for (int m = 0; m < 4; ++m)
            af[m] = *(const bf16x8*)&As[(wr * 64 + m * 16 + lr) * 32 + lk];
#pragma unroll
        for (int n = 0; n < 2; ++n)
            bfr[n] = *(const bf16x8*)&Bs[(wc * 32 + n * 16 + lr) * 32 + lk];
#pragma unroll
        for (int m = 0; m < 4; ++m)
#pragma unroll
            for (int n = 0; n < 2; ++n)
                acc[m][n] = __builtin_amdgcn_mfma_f32_16x16x32_bf16(
                    af[m], bfr[n], acc[m][n], 0, 0, 0);
    }

    const int mBase = m0 + wr * 64, nBase = n0 + wc * 32;
    float scn[2];
#pragma unroll
    for (int n = 0; n < 2; ++n) {
        const int col = nBase + n * 16 + lr;
        const float4 pv = *(const float4*)(rs + (size_t)col * 4);
        scn[n] = rsqrtf((pv.x + pv.y + pv.z + pv.w) * (1.f / 1024.f) + 1e-5f);
    }
#pragma unroll
    for (int m = 0; m < 4; ++m) {
#pragma unroll
        for (int j = 0; j < 4; ++j) {
            const int row = mBase + m * 16 + (ln >> 4) * 4 + j;
            const float rb = bias[row];
#pragma unroll
            for (int n = 0; n < 2; ++n) {
                const int col = nBase + n * 16 + lr;
                Cf[(size_t)row * ldc + col] = acc[m][n][j] * scn[n] + rb;
            }
        }
    }
}

// ---------------------------------------------------------------------------
// Merged prep:
//  [0,128):      Wc[h][c] = sum_d ip[DTOFF+h][d]*pi[d][c] (fp32; waves split d)
//                + bc[h] = sum_d pib[d]*ip[DTOFF+h][d]     (on c0==0 blocks)
//  [128,896):    weights -> bf16: wpi, wpo, wip (2176 rows) grid-stride
//  [896,1408):   wopT[d][o] = bf16(op[o][d] * nw[d])        32x32 tiles
//  [1408,3456):  hsT[v][c] = bf16(hs[c][v])                 32x32 tiles
// ---------------------------------------------------------------------------
#define SZ_PI  (512 * 512)
#define SZ_PO  (512 * 512)
#define SZ_IP2 (ZLD * 512)
#define SZ_ALL (SZ_PI + SZ_PO + SZ_IP2)
#define NB_WC  128
#define NB_WB  768
#define NB_WT  512
#define NB_HT  2048
#define NB_ALL (NB_WC + NB_WB + NB_WT + NB_HT)

__global__ __launch_bounds__(256) void prep_all(
    const float* __restrict__ pi, const float* __restrict__ po,
    const float* __restrict__ op, const float* __restrict__ ip,
    const float* __restrict__ nw, const float* __restrict__ pib,
    const float* __restrict__ hs,
    bf16* __restrict__ wpi, bf16* __restrict__ wpo, bf16* __restrict__ wip,
    bf16* __restrict__ wopT, bf16* __restrict__ hsT,
    float* __restrict__ Wc, float* __restrict__ bc)
{
    __shared__ float smem[32 * 33];
    const int b = blockIdx.x, tid = threadIdx.x;

    if (b < NB_WC) {
        const int h = b >> 3, c0 = (b & 7) * 64;
        const int w = tid >> 6, l = tid & 63;
        const float* wdt = ip + (size_t)(DTOFF + h) * DMODEL;
        float acc = 0.f;
#pragma unroll 8
        for (int i = 0; i < 128; ++i) {
            const int d = w * 128 + i;
            acc = fmaf(wdt[d], pi[(size_t)d * DMODEL + c0 + l], acc);
        }
        smem[w * 64 + l] = acc;
        __syncthreads();
        if (tid < 64)
            Wc[(size_t)h * DMODEL + c0 + tid] =
                smem[tid] + smem[64 + tid] + smem[128 + tid] + smem[192 + tid];
        if ((b & 7) == 0) {
            float p = pib[tid] * wdt[tid] + pib[tid + 256] * wdt[tid + 256];
#pragma unroll
            for (int off = 32; off >= 1; off >>= 1) p += __shfl_xor(p, off);
            if ((tid & 63) == 0) smem[300 + (tid >> 6)] = p;
            __syncthreads();
            if (tid == 0)
                bc[h] = smem[300] + smem[301] + smem[302] + smem[303];
        }
    } else if (b < NB_WC + NB_WB) {
        const int wb = b - NB_WC;
        for (int idx = wb * 256 + tid; idx < SZ_ALL; idx += NB_WB * 256) {
            if (idx < SZ_PI) {
                wpi[idx] = __float2bfloat16(pi[idx]);
            } else if (idx < SZ_PI + SZ_PO) {
                int j = idx - SZ_PI; wpo[j] = __float2bfloat16(po[j]);
            } else {
                int j = idx - SZ_PI - SZ_PO;
                wip[j] = __float2bfloat16(ip[j]);   // rows 0..2175 only
            }
        }
    } else if (b < NB_WC + NB_WB + NB_WT) {
        // wopT[d][o] = op[o][d] * nw[d]  (bf16); op is [512 o][1024 d]
        const int tb = b - NB_WC - NB_WB;
        const int o0 = (tb & 15) * 32, d0 = (tb >> 4) * 32;
        const int tx = tid & 31, ty = tid >> 5;
#pragma unroll
        for (int i = 0; i < 4; ++i)
            smem[(ty + 8 * i) * 33 + tx] =
                op[(size_t)(o0 + ty + 8 * i) * DINNER + d0 + tx];
        __syncthreads();
#pragma unroll
        for (int i = 0; i < 4; ++i) {
            const int d = d0 + ty + 8 * i;
            wopT[(size_t)d * DMODEL + o0 + tx] =
                __float2bfloat16(smem[tx * 33 + ty + 8 * i] * nw[d]);
        }
    } else {
        // hsT[v][c] = hs[c][v] (bf16)
        const int tb = b - NB_WC - NB_WB - NB_WT;
        const int v0 = (tb & 127) * 32, c0 = (tb >> 7) * 32;
        const int tx = tid & 31, ty = tid >> 5;
#pragma unroll
        for (int i = 0; i < 4; ++i)
            smem[(ty + 8 * i) * 33 + tx] =
                hs[(size_t)(c0 + ty + 8 * i) * TOK + v0 + tx];
        __syncthreads();
#pragma unroll
        for (int i = 0; i < 4; ++i)
            hsT[(size_t)(v0 + ty + 8 * i) * DMODEL + c0 + tx] =
                __float2bfloat16(smem[tx * 33 + ty + 8 * i]);
    }
}

// ---------------------------------------------------------------------------
// Merged P2 + K1 (both depend only on prep):
//  blocks [0,64):    Wbig[c][d] = wpo[c][:] . wopT[d][:]         (4 x 16)
//  blocks [64,320):  xv_bf[v][d] = hsT[v][:] . wpi[d][:] + b[d]  (32 x 8)
// ---------------------------------------------------------------------------
__global__ __launch_bounds__(256) void gemm_p2k1(
    const bf16* __restrict__ wpo, const bf16* __restrict__ wopT,
    const bf16* __restrict__ hsT, const bf16* __restrict__ wpi,
    const float* __restrict__ pib,
    bf16* __restrict__ Wbig, bf16* __restrict__ xv_bf)
{
    __shared__ short As[128 * 32];
    __shared__ short Bs[64 * 32];
    const int b = blockIdx.x;
    if (b < 64) {
        gemm_core<2>(As, Bs, wpo, wopT, nullptr, Wbig,
                     b & 3, b >> 2, DMODEL, DMODEL, DMODEL, DINNER, DINNER);
    } else {
        const int b2 = b - 64;
        gemm_core<2>(As, Bs, hsT, wpi, pib, xv_bf,
                     b2 & 31, b2 >> 5, DMODEL, DMODEL, DMODEL, DMODEL, DMODEL);
    }
}

// ---------------------------------------------------------------------------
// Merged K2 + dt (dt depends only on prep; K2 on gemm_p2k1):
//  blocks [0,544):    zb[v][e] = xv[v][:] . wip[e][:]  (32 x 17, N=2176 exact)
//  blocks [544,4640): dtf[v][h] = hsT[v][:] . Wc[h][:] + bc[h]  (fp32 acc)
// ---------------------------------------------------------------------------
__global__ __launch_bounds__(256) void k2_dt(
    const bf16* __restrict__ xv_bf, const bf16* __restrict__ wip,
    const bf16* __restrict__ hsT, const float* __restrict__ Wc,
    const float* __restrict__ bc,
    bf16* __restrict__ zb, float* __restrict__ dtf)
{
    __shared__ short As[128 * 32];
    __shared__ short Bs[128 * 32];
    const int b = blockIdx.x;
    if (b < 544) {
        gemm_core<4>(As, Bs, xv_bf, wip, nullptr, zb,
                     b & 31, b >> 5, DMODEL, DMODEL, DMODEL, ZLD, ZLD);
    } else {
        const int v = b - 544;
        const int w = threadIdx.x >> 6, l = threadIdx.x & 63;
        const bf16x8 hv = *(const bf16x8*)(hsT + (size_t)v * DMODEL + l * 8);
        float hf[8];
#pragma unroll
        for (int j = 0; j < 8; ++j) {
            const unsigned int bits = ((unsigned int)(unsigned short)hv[j]) << 16;
            hf[j] = __uint_as_float(bits);
        }
#pragma unroll
        for (int hh = 0; hh < 4; ++hh) {
            const int h = w * 4 + hh;
            const float4* wr = (const float4*)(Wc + (size_t)h * DMODEL);
            const float4 w0 = wr[l * 2], w1 = wr[l * 2 + 1];
            float dot = hf[0] * w0.x + hf[1] * w0.y + hf[2] * w0.z + hf[3] * w0.w
                      + hf[4] * w1.x + hf[5] * w1.y + hf[6] * w1.z + hf[7] * w1.w;
#pragma unroll
            for (int off = 32; off >= 1; off >>= 1) dot += __shfl_xor(dot, off);
            if (l == 0) dtf[(size_t)v * 16 + h] = dot + bc[h];
        }
    }
}

// ---------------------------------------------------------------------------
// Fused conv + SSD + D-skip + z-gating; emits unnormalized g (bf16) and
// per-(token, head-quad) partial sum-of-squares.
// Grid (n, hq): 256 x 4 blocks, 256 threads = 4 waves; wave w = head hq*4+w.
// SSD (exact for T=16):
//   y_t[p] = sum_{s<=t} exp(a*(cum_t - cum_s)) * (C_t . B_s) * dt_s * x_s[p]
// ---------------------------------------------------------------------------
__global__ __launch_bounds__(256) void ssd_kernel(
    const bf16* __restrict__ zb, const float* __restrict__ dtf,
    const float* __restrict__ conv_w, const float* __restrict__ conv_b,
    const float* __restrict__ dt_bias, const float* __restrict__ A_log,
    const float* __restrict__ Dp,
    bf16* __restrict__ gb, float* __restrict__ part)
{
    const int n = blockIdx.x, hq = blockIdx.y;
    const int tid = threadIdx.x;
    const int w = tid >> 6, p = tid & 63;
    const int h = hq * 4 + w;
    const int ch = hq * 256 + tid;          // x / z / g channel

    __shared__ float Bsh[16][68];           // [t][state]
    __shared__ float Csh[16][68];
    __shared__ float Gsh[16][16];           // [t][s] = C_t . B_s
    __shared__ float Msh[4][256];           // per-wave mask [t*16+s]
    __shared__ float red4[16][4];           // [t][wave] partial sumsq

    // ---- phase 0: load x-part (bf16) for own channel, all 16 t ----
    float ld[16];
#pragma unroll
    for (int t = 0; t < 16; ++t)
        ld[t] = __bfloat162float(zb[(size_t)(t * 256 + n) * ZLD + 1024 + ch]);

    const float cw0 = conv_w[ch * 4 + 0], cw1 = conv_w[ch * 4 + 1],
                cw2 = conv_w[ch * 4 + 2], cw3 = conv_w[ch * 4 + 3];
    const float cb = conv_b[ch];
    float xs[16];
#pragma unroll
    for (int t = 0; t < 16; ++t) {
        float a = fmaf(ld[t], cw3, cb);
        if (t >= 1) a = fmaf(ld[t - 1], cw2, a);
        if (t >= 2) a = fmaf(ld[t - 2], cw1, a);
        if (t >= 3) a = fmaf(ld[t - 3], cw0, a);
        xs[t] = a / (1.f + __expf(-a));
    }

    // ---- conv B/C channels (cols 2048..2175) by threads 0..127 ----
    if (tid < 128) {
        const int cc = 1024 + tid;
        const float dw0 = conv_w[cc * 4 + 0], dw1 = conv_w[cc * 4 + 1],
                    dw2 = conv_w[cc * 4 + 2], dw3 = conv_w[cc * 4 + 3];
        const float db = conv_b[cc];
        float q0 = 0.f, q1 = 0.f, q2 = 0.f;
#pragma unroll
        for (int t = 0; t < 16; ++t) {
            const float cur =
                __bfloat162float(zb[(size_t)(t * 256 + n) * ZLD + 2048 + tid]);
            float a = fmaf(cur, dw3, db);
            a = fmaf(q2, dw2, a);
            a = fmaf(q1, dw1, a);
            a = fmaf(q0, dw0, a);
            const float val = a / (1.f + __expf(-a));
            if (tid < 64) Bsh[t][tid] = val; else Csh[t][tid - 64] = val;
            q0 = q1; q1 = q2; q2 = cur;
        }
    }

    // ---- per-head dt (softplus, fp32) + inclusive cumsum over t ----
    const float a_h = -__expf(A_log[h]);
    float dtv_l = 0.f;
    if (p < 16) {
        const float raw = dtf[(size_t)(p * 256 + n) * 16 + h] + dt_bias[h];
        dtv_l = (raw > 20.f) ? raw : log1pf(__expf(raw));
    }
    float cum_l = dtv_l;
#pragma unroll
    for (int off = 1; off < 16; off <<= 1) {
        const float tmp = __shfl_up(cum_l, off);
        if (p >= off) cum_l += tmp;
    }
    __syncthreads();   // Bsh/Csh ready

    // ---- G[t][s] = C_t . B_s (head-independent) ----
    {
        const int t = tid >> 4, s = tid & 15;
        float acc = 0.f;
#pragma unroll
        for (int k = 0; k < 64; ++k)
            acc = fmaf(Csh[t][k], Bsh[s][k], acc);
        Gsh[t][s] = acc;
    }
    __syncthreads();

    // ---- per-head mask M[t][s] = exp(a*(cum_t-cum_s)) * G * dt_s ----
    float dtv_all[16], cum_all[16];
#pragma unroll
    for (int t = 0; t < 16; ++t) {
        dtv_all[t] = __shfl(dtv_l, t);
        cum_all[t] = __shfl(cum_l, t);
    }
#pragma unroll
    for (int q = 0; q < 4; ++q) {
        const int idx = p * 4 + q;
        const int t = idx >> 4, s = idx & 15;
        float m = 0.f;
        if (s <= t)
            m = __expf(a_h * (cum_all[t] - cum_all[s])) * Gsh[t][s] * dtv_all[s];
        Msh[w][idx] = m;   // wave-private; no barrier needed
    }

    // issue z loads; latency hides under phase 4 compute
    float zl[16];
#pragma unroll
    for (int t = 0; t < 16; ++t)
        zl[t] = __bfloat162float(zb[(size_t)(t * 256 + n) * ZLD + ch]);

    // ---- Y = M . x + D*x, gate with silu(z) ----
    const float Dh = Dp[h];
    float g[16];
#pragma unroll
    for (int t = 0; t < 16; ++t) {
        float y = 0.f;
#pragma unroll
        for (int s = 0; s <= t; ++s)
            y = fmaf(Msh[w][t * 16 + s], xs[s], y);
        y = fmaf(Dh, xs[t], y);
        g[t] = y * (zl[t] / (1.f + __expf(-zl[t])));
    }

    // ---- partial sum of squares per (t, wave) + write g ----
#pragma unroll
    for (int t = 0; t < 16; ++t) {
        float ss = g[t] * g[t];
#pragma unroll
        for (int off = 32; off >= 1; off >>= 1) ss += __shfl_xor(ss, off);
        if (p == 0) red4[t][w] = ss;
        gb[(size_t)(t * 256 + n) * DINNER + ch] = __float2bfloat16(g[t]);
    }
    __syncthreads();
    if (tid < 16)
        part[(size_t)(tid * 256 + n) * 4 + hq] =
            red4[tid][0] + red4[tid][1] + red4[tid][2] + red4[tid][3];
}

// ---------------------------------------------------------------------------
extern "C" void kernel_launch(void* const* d_in, const int* in_sizes, int n_in,
                              void* d_out, int out_size, void* d_ws, size_t ws_size,
                              hipStream_t stream) {
    const float* hs         = (const float*)d_in[0];   // (1,512,16,16,16)
    const float* proj_in_w  = (const float*)d_in[1];   // (512,512)
    const float* proj_in_b  = (const float*)d_in[2];   // (512)
    const float* proj_out_w = (const float*)d_in[3];   // (512,512)
    const float* proj_out_b = (const float*)d_in[4];   // (512)
    const float* in_proj_w  = (const float*)d_in[5];   // (2192,512)
    const float* conv_w     = (const float*)d_in[6];   // (1152,4)
    const float* conv_b     = (const float*)d_in[7];   // (1152)
    const float* dt_bias    = (const float*)d_in[8];   // (16)
    const float* A_log      = (const float*)d_in[9];   // (16)
    const float* Dp         = (const float*)d_in[10];  // (16)
    const float* norm_w     = (const float*)d_in[11];  // (1024)
    const float* out_proj_w = (const float*)d_in[12];  // (512,1024)
    float* out = (float*)d_out;

    // workspace layout (fp32 first, then bf16)
    float* ws      = (float*)d_ws;
    float* dtf     = ws;                                   // 4096*16 f32
    float* part    = dtf + (size_t)TOK * 16;               // 4096*4  f32
    float* Wc      = part + (size_t)TOK * 4;               // 16*512  f32
    float* bc      = Wc + 16 * DMODEL;                     // 16      f32
    bf16*  hsT     = (bf16*)(bc + 16);                     // 4096*512
    bf16*  xv_bf   = hsT + (size_t)TOK * DMODEL;           // 4096*512
    bf16*  zb      = xv_bf + (size_t)TOK * DMODEL;         // 4096*2176
    bf16*  gb      = zb + (size_t)TOK * ZLD;               // 4096*1024
    bf16*  wpi     = gb + (size_t)TOK * DINNER;            // 512*512
    bf16*  wpo     = wpi + SZ_PI;                          // 512*512
    bf16*  wip     = wpo + SZ_PO;                          // 2176*512
    bf16*  wopT    = wip + SZ_IP2;                         // 1024*512 (nw folded)
    bf16*  Wbig    = wopT + (size_t)DINNER * DMODEL;       // 512*1024

    // D1: Wc/bc (fp32), weights -> bf16, wopT (nw folded), hs -> hsT
    prep_all<<<NB_ALL, 256, 0, stream>>>(
        proj_in_w, proj_out_w, out_proj_w, in_proj_w, norm_w, proj_in_b, hs,
        wpi, wpo, wip, wopT, hsT, Wc, bc);

    // D2: Wbig = wpo . wopT^T  and  xv_bf = hsT . wpi^T + b   (merged)
    gemm_p2k1<<<320, 256, 0, stream>>>(
        wpo, wopT, hsT, wpi, proj_in_b, Wbig, xv_bf);

    // D3: zb = xv . wip^T (bf16)  and  dtf = hsT . Wc^T + bc (fp32)  (merged)
    k2_dt<<<544 + TOK, 256, 0, stream>>>(
        xv_bf, wip, hsT, Wc, bc, zb, dtf);

    // D4: fused conv + SSD + gate -> gb (bf16) + partial sumsq
    ssd_kernel<<<dim3(NSEQ, 4), 256, 0, stream>>>(
        zb, dtf, conv_w, conv_b, dt_bias, A_log, Dp, gb, part);

    // D5: out[c][v] = scale[v] * (Wbig[c][:] . gb[v][:]) + pob[c]
    k67_gemm<<<dim3(4, 64), 256, 0, stream>>>(
        Wbig, gb, proj_out_b, part, out, DINNER, DINNER, DINNER, TOK);
}

// Round 14
// 99.968 us; speedup vs baseline: 1.2105x; 1.0046x over previous
//
#include <hip/hip_runtime.h>
#include <hip/hip_bf16.h>
#include <math.h>

// Problem constants
#define TT       16      // sequence length T
#define NSEQ     256     // B*H*W sequences
#define TOK      4096    // NSEQ * TT tokens
#define DMODEL   512
#define DINNER   1024
#define DSTATE   64
#define NHEADS   16
#define HEADDIM  64
#define CONVDIM  1152    // D_INNER + 2*D_STATE
#define DINPROJ  2192    // full in_proj rows
#define DTOFF    2176    // start of dt rows in in_proj
#define ZLD      2176    // zb row stride (z:0..1023, xBC:1024..2175)

using bf16x8 = __attribute__((ext_vector_type(8))) short;
using f32x4  = __attribute__((ext_vector_type(4))) float;
typedef __hip_bfloat16 bf16;

__device__ __forceinline__ void gload_lds16(const void* g, void* l) {
    __builtin_amdgcn_global_load_lds(
        (const __attribute__((address_space(1))) unsigned int*)g,
        (__attribute__((address_space(3))) unsigned int*)l,
        16, 0, 0);
}

// ---------------------------------------------------------------------------
// GEMM core (device fn): C[M][N] = A[M][K]*B[N][K]^T (+ bias[col]), bf16 out.
// Tile 128 x (NFRAG*32), BK=32, 256 threads (4 waves, 2x2 wave grid).
// ---------------------------------------------------------------------------
template<int NFRAG>
__device__ __forceinline__ void gemm_core(
    short* As, short* Bs,
    const bf16* __restrict__ A, const bf16* __restrict__ B,
    const float* __restrict__ bias, bf16* __restrict__ Ch,
    int bm, int bn, int K, int lda, int ldb, int ldc, int Nreal)
{
    constexpr int BN = NFRAG * 32;
    const int tid = threadIdx.x;
    const int wv = tid >> 6, ln = tid & 63;
    const int m0 = bm * 128, n0 = bn * BN;
    const int wr = wv >> 1, wc = wv & 1;
    const int lr = ln & 15, lk = (ln >> 4) * 8;

    f32x4 acc[4][NFRAG];
#pragma unroll
    for (int m = 0; m < 4; ++m)
#pragma unroll
        for (int n = 0; n < NFRAG; ++n) acc[m][n] = (f32x4){0.f, 0.f, 0.f, 0.f};

    for (int k0 = 0; k0 < K; k0 += 32) {
        __syncthreads();
#pragma unroll
        for (int r = 0; r < 2; ++r) {
            const int ofs = r * 4096 + tid * 16;
            const int row = ofs >> 6;
            const int ke  = (ofs & 63) >> 1;
            gload_lds16(A + (size_t)(m0 + row) * lda + k0 + ke, (char*)As + ofs);
        }
#pragma unroll
        for (int r = 0; r < NFRAG / 2; ++r) {
            const int ofs = r * 4096 + tid * 16;
            const int row = ofs >> 6;
            const int ke  = (ofs & 63) >> 1;
            gload_lds16(B + (size_t)(n0 + row) * ldb + k0 + ke, (char*)Bs + ofs);
        }
        __syncthreads();

        bf16x8 af[4], bfr[NFRAG];
#pragma unroll
        for (int m = 0; m < 4; ++m)
            af[m] = *(const bf16x8*)&As[(wr * 64 + m * 16 + lr) * 32 + lk];
#pragma unroll
        for (int n = 0; n < NFRAG; ++n)
            bfr[n] = *(const bf16x8*)&Bs[(wc * (BN / 2) + n * 16 + lr) * 32 + lk];
#pragma unroll
        for (int m = 0; m < 4; ++m)
#pragma unroll
            for (int n = 0; n < NFRAG; ++n)
                acc[m][n] = __builtin_amdgcn_mfma_f32_16x16x32_bf16(
                    af[m], bfr[n], acc[m][n], 0, 0, 0);
    }

    const int mBase = m0 + wr * 64, nBase = n0 + wc * (BN / 2);
    float cbv[NFRAG];
#pragma unroll
    for (int n = 0; n < NFRAG; ++n) {
        const int col = nBase + n * 16 + lr;
        cbv[n] = (bias != nullptr && col < Nreal) ? bias[col] : 0.f;
    }
#pragma unroll
    for (int m = 0; m < 4; ++m) {
#pragma unroll
        for (int j = 0; j < 4; ++j) {
            const int row = mBase + m * 16 + (ln >> 4) * 4 + j;
#pragma unroll
            for (int n = 0; n < NFRAG; ++n) {
                const int col = nBase + n * 16 + lr;
                if (col < Nreal)
                    Ch[(size_t)row * ldc + col] =
                        __float2bfloat16(acc[m][n][j] + cbv[n]);
            }
        }
    }
}

// ---------------------------------------------------------------------------
// Standalone MFMA GEMM for K67: fp32 out, per-row bias, per-col RMS scale.
// out[c][v] = rsqrt(mean part[v] + eps) * (A[c][:] . B[v][:]) + bias[c]
// ---------------------------------------------------------------------------
__global__ __launch_bounds__(256) void k67_gemm(
    const bf16* __restrict__ A, const bf16* __restrict__ B,
    const float* __restrict__ bias, const float* __restrict__ rs,
    float* __restrict__ Cf, int K, int lda, int ldb, int ldc)
{
    __shared__ short As[128 * 32];
    __shared__ short Bs[64 * 32];

    const int tid = threadIdx.x;
    const int wv = tid >> 6, ln = tid & 63;
    const int m0 = blockIdx.x * 128, n0 = blockIdx.y * 64;
    const int wr = wv >> 1, wc = wv & 1;
    const int lr = ln & 15, lk = (ln >> 4) * 8;

    f32x4 acc[4][2];
#pragma unroll
    for (int m = 0; m < 4; ++m)
#pragma unroll
        for (int n = 0; n < 2; ++n) acc[m][n] = (f32x4){0.f, 0.f, 0.f, 0.f};

    for (int k0 = 0; k0 < K; k0 += 32) {
        __syncthreads();
#pragma unroll
        for (int r = 0; r < 2; ++r) {
            const int ofs = r * 4096 + tid * 16;
            const int row = ofs >> 6;
            const int ke  = (ofs & 63) >> 1;
            gload_lds16(A + (size_t)(m0 + row) * lda + k0 + ke, (char*)As + ofs);
        }
        {
            const int ofs = tid * 16;
            const int row = ofs >> 6;
            const int ke  = (ofs & 63) >> 1;
            gload_lds16(B + (size_t)(n0 + row) * ldb + k0 + ke, (char*)Bs + ofs);
        }
        __syncthreads();

        bf16x8 af[4], bfr[2];
#pragma unroll
        for (int m = 0; m < 4; ++m)
            af[m] = *(const bf16x8*)&As[(wr * 64 + m * 16 + lr) * 32 + lk];
#pragma unroll
        for (int n = 0; n < 2; ++n)
            bfr[n] = *(const bf16x8*)&Bs[(wc * 32 + n * 16 + lr) * 32 + lk];
#pragma unroll
        for (int m = 0; m < 4; ++m)
#pragma unroll
            for (int n = 0; n < 2; ++n)
                acc[m][n] = __builtin_amdgcn_mfma_f32_16x16x32_bf16(
                    af[m], bfr[n], acc[m][n], 0, 0, 0);
    }

    const int mBase = m0 + wr * 64, nBase = n0 + wc * 32;
    float scn[2];
#pragma unroll
    for (int n = 0; n < 2; ++n) {
        const int col = nBase + n * 16 + lr;
        const float4 pv = *(const float4*)(rs + (size_t)col * 4);
        scn[n] = rsqrtf((pv.x + pv.y + pv.z + pv.w) * (1.f / 1024.f) + 1e-5f);
    }
#pragma unroll
    for (int m = 0; m < 4; ++m) {
#pragma unroll
        for (int j = 0; j < 4; ++j) {
            const int row = mBase + m * 16 + (ln >> 4) * 4 + j;
            const float rb = bias[row];
#pragma unroll
            for (int n = 0; n < 2; ++n) {
                const int col = nBase + n * 16 + lr;
                Cf[(size_t)row * ldc + col] = acc[m][n][j] * scn[n] + rb;
            }
        }
    }
}

// ---------------------------------------------------------------------------
// Merged prep:
//  [0,128):       Wc[h][c] = sum_d ip[DTOFF+h][d]*pi[d][c] (fp32; waves split d)
//                 + bc[h] (on c0==0 blocks)
//  [128,672):     zbias[e] = sum_d pib[d]*ip[e][d]   (wave per e, lane=d)
//  [672,1440):    weights -> bf16: wpo, wip (2176 rows)  grid-stride
//  [1440,1696):   wpiT[c][d] = bf16(pi[d][c])            32x32 tiles
//  [1696,2208):   wopT[d][o] = bf16(op[o][d] * nw[d])    32x32 tiles
//  [2208,4256):   hsT[v][c] = bf16(hs[c][v])             32x32 tiles
// ---------------------------------------------------------------------------
#define SZ_PO  (512 * 512)
#define SZ_IP2 (ZLD * 512)
#define SZ_ALL (SZ_PO + SZ_IP2)
#define NB_WC  128
#define NB_ZB  544
#define NB_WB  768
#define NB_PT  256
#define NB_WT  512
#define NB_HT  2048
#define NB_ALL (NB_WC + NB_ZB + NB_WB + NB_PT + NB_WT + NB_HT)

__global__ __launch_bounds__(256) void prep_all(
    const float* __restrict__ pi, const float* __restrict__ po,
    const float* __restrict__ op, const float* __restrict__ ip,
    const float* __restrict__ nw, const float* __restrict__ pib,
    const float* __restrict__ hs,
    bf16* __restrict__ wpo, bf16* __restrict__ wip,
    bf16* __restrict__ wpiT, bf16* __restrict__ wopT, bf16* __restrict__ hsT,
    float* __restrict__ Wc, float* __restrict__ bc, float* __restrict__ zbias)
{
    __shared__ float smem[32 * 33];
    const int b = blockIdx.x, tid = threadIdx.x;

    if (b < NB_WC) {
        const int h = b >> 3, c0 = (b & 7) * 64;
        const int w = tid >> 6, l = tid & 63;
        const float* wdt = ip + (size_t)(DTOFF + h) * DMODEL;
        float acc = 0.f;
#pragma unroll 8
        for (int i = 0; i < 128; ++i) {
            const int d = w * 128 + i;
            acc = fmaf(wdt[d], pi[(size_t)d * DMODEL + c0 + l], acc);
        }
        smem[w * 64 + l] = acc;
        __syncthreads();
        if (tid < 64)
            Wc[(size_t)h * DMODEL + c0 + tid] =
                smem[tid] + smem[64 + tid] + smem[128 + tid] + smem[192 + tid];
        if ((b & 7) == 0) {
            float p = pib[tid] * wdt[tid] + pib[tid + 256] * wdt[tid + 256];
#pragma unroll
            for (int off = 32; off >= 1; off >>= 1) p += __shfl_xor(p, off);
            if ((tid & 63) == 0) smem[300 + (tid >> 6)] = p;
            __syncthreads();
            if (tid == 0)
                bc[h] = smem[300] + smem[301] + smem[302] + smem[303];
        }
    } else if (b < NB_WC + NB_ZB) {
        // zbias[e] = pib . ip[e][:]  — one wave per row, lane = d (coalesced)
        const int e = (b - NB_WC) * 4 + (tid >> 6);
        const int l = tid & 63;
        const float* row = ip + (size_t)e * DMODEL;
        float acc = 0.f;
#pragma unroll
        for (int i = 0; i < 8; ++i)
            acc = fmaf(pib[l + i * 64], row[l + i * 64], acc);
#pragma unroll
        for (int off = 32; off >= 1; off >>= 1) acc += __shfl_xor(acc, off);
        if (l == 0) zbias[e] = acc;
    } else if (b < NB_WC + NB_ZB + NB_WB) {
        const int wb = b - NB_WC - NB_ZB;
        for (int idx = wb * 256 + tid; idx < SZ_ALL; idx += NB_WB * 256) {
            if (idx < SZ_PO) {
                wpo[idx] = __float2bfloat16(po[idx]);
            } else {
                int j = idx - SZ_PO;
                wip[j] = __float2bfloat16(ip[j]);   // rows 0..2175 only
            }
        }
    } else if (b < NB_WC + NB_ZB + NB_WB + NB_PT) {
        // wpiT[c][d] = pi[d][c] (bf16)
        const int tb = b - NB_WC - NB_ZB - NB_WB;
        const int c0 = (tb & 15) * 32, d0 = (tb >> 4) * 32;
        const int tx = tid & 31, ty = tid >> 5;
#pragma unroll
        for (int i = 0; i < 4; ++i)
            smem[(ty + 8 * i) * 33 + tx] =
                pi[(size_t)(d0 + ty + 8 * i) * DMODEL + c0 + tx];
        __syncthreads();
#pragma unroll
        for (int i = 0; i < 4; ++i)
            wpiT[(size_t)(c0 + ty + 8 * i) * DMODEL + d0 + tx] =
                __float2bfloat16(smem[tx * 33 + ty + 8 * i]);
    } else if (b < NB_WC + NB_ZB + NB_WB + NB_PT + NB_WT) {
        // wopT[d][o] = op[o][d] * nw[d]  (bf16); op is [512 o][1024 d]
        const int tb = b - NB_WC - NB_ZB - NB_WB - NB_PT;
        const int o0 = (tb & 15) * 32, d0 = (tb >> 4) * 32;
        const int tx = tid & 31, ty = tid >> 5;
#pragma unroll
        for (int i = 0; i < 4; ++i)
            smem[(ty + 8 * i) * 33 + tx] =
                op[(size_t)(o0 + ty + 8 * i) * DINNER + d0 + tx];
        __syncthreads();
#pragma unroll
        for (int i = 0; i < 4; ++i) {
            const int d = d0 + ty + 8 * i;
            wopT[(size_t)d * DMODEL + o0 + tx] =
                __float2bfloat16(smem[tx * 33 + ty + 8 * i] * nw[d]);
        }
    } else {
        // hsT[v][c] = hs[c][v] (bf16)
        const int tb = b - NB_WC - NB_ZB - NB_WB - NB_PT - NB_WT;
        const int v0 = (tb & 127) * 32, c0 = (tb >> 7) * 32;
        const int tx = tid & 31, ty = tid >> 5;
#pragma unroll
        for (int i = 0; i < 4; ++i)
            smem[(ty + 8 * i) * 33 + tx] =
                hs[(size_t)(c0 + ty + 8 * i) * TOK + v0 + tx];
        __syncthreads();
#pragma unroll
        for (int i = 0; i < 4; ++i)
            hsT[(size_t)(v0 + ty + 8 * i) * DMODEL + c0 + tx] =
                __float2bfloat16(smem[tx * 33 + ty + 8 * i]);
    }
}

// ---------------------------------------------------------------------------
// Stage 2 (depends only on prep): weight-product GEMMs.
//  blocks [0,64):    Wbig[c][d]  = wpo[c][:] . wopT[d][:]   (4 x 16, NFRAG=2)
//  blocks [64,200):  Wfuse[e][c] = wip[e][:] . wpiT[c][:]   (17 x 8, NFRAG=2)
// ---------------------------------------------------------------------------
__global__ __launch_bounds__(256) void gemm_w(
    const bf16* __restrict__ wpo, const bf16* __restrict__ wopT,
    const bf16* __restrict__ wip, const bf16* __restrict__ wpiT,
    bf16* __restrict__ Wbig, bf16* __restrict__ Wfuse)
{
    __shared__ short As[128 * 32];
    __shared__ short Bs[64 * 32];
    const int b = blockIdx.x;
    if (b < 64) {
        gemm_core<2>(As, Bs, wpo, wopT, nullptr, Wbig,
                     b & 3, b >> 2, DMODEL, DMODEL, DMODEL, DINNER, DINNER);
    } else {
        const int b2 = b - 64;
        gemm_core<2>(As, Bs, wip, wpiT, nullptr, Wfuse,
                     b2 >> 3, b2 & 7, DMODEL, DMODEL, DMODEL, DMODEL, DMODEL);
    }
}

// ---------------------------------------------------------------------------
// Stage 3: K2 + dt.
//  blocks [0,544):    zb[v][e] = hsT[v][:] . Wfuse[e][:] + zbias[e]
//  blocks [544,4640): dtf[v][h] = hsT[v][:] . Wc[h][:] + bc[h]  (fp32 acc)
// ---------------------------------------------------------------------------
__global__ __launch_bounds__(256) void k2_dt(
    const bf16* __restrict__ hsT, const bf16* __restrict__ Wfuse,
    const float* __restrict__ zbias, const float* __restrict__ Wc,
    const float* __restrict__ bc,
    bf16* __restrict__ zb, float* __restrict__ dtf)
{
    __shared__ short As[128 * 32];
    __shared__ short Bs[128 * 32];
    const int b = blockIdx.x;
    if (b < 544) {
        gemm_core<4>(As, Bs, hsT, Wfuse, zbias, zb,
                     b & 31, b >> 5, DMODEL, DMODEL, DMODEL, ZLD, ZLD);
    } else {
        const int v = b - 544;
        const int w = threadIdx.x >> 6, l = threadIdx.x & 63;
        const bf16x8 hv = *(const bf16x8*)(hsT + (size_t)v * DMODEL + l * 8);
        float hf[8];
#pragma unroll
        for (int j = 0; j < 8; ++j) {
            const unsigned int bits = ((unsigned int)(unsigned short)hv[j]) << 16;
            hf[j] = __uint_as_float(bits);
        }
#pragma unroll
        for (int hh = 0; hh < 4; ++hh) {
            const int h = w * 4 + hh;
            const float4* wr = (const float4*)(Wc + (size_t)h * DMODEL);
            const float4 w0 = wr[l * 2], w1 = wr[l * 2 + 1];
            float dot = hf[0] * w0.x + hf[1] * w0.y + hf[2] * w0.z + hf[3] * w0.w
                      + hf[4] * w1.x + hf[5] * w1.y + hf[6] * w1.z + hf[7] * w1.w;
#pragma unroll
            for (int off = 32; off >= 1; off >>= 1) dot += __shfl_xor(dot, off);
            if (l == 0) dtf[(size_t)v * 16 + h] = dot + bc[h];
        }
    }
}

// ---------------------------------------------------------------------------
// Fused conv + SSD + D-skip + z-gating; emits unnormalized g (bf16) and
// per-(token, head-quad) partial sum-of-squares.
// Grid (n, hq): 256 x 4 blocks, 256 threads = 4 waves; wave w = head hq*4+w.
// SSD (exact for T=16):
//   y_t[p] = sum_{s<=t} exp(a*(cum_t - cum_s)) * (C_t . B_s) * dt_s * x_s[p]
// ---------------------------------------------------------------------------
__global__ __launch_bounds__(256) void ssd_kernel(
    const bf16* __restrict__ zb, const float* __restrict__ dtf,
    const float* __restrict__ conv_w, const float* __restrict__ conv_b,
    const float* __restrict__ dt_bias, const float* __restrict__ A_log,
    const float* __restrict__ Dp,
    bf16* __restrict__ gb, float* __restrict__ part)
{
    const int n = blockIdx.x, hq = blockIdx.y;
    const int tid = threadIdx.x;
    const int w = tid >> 6, p = tid & 63;
    const int h = hq * 4 + w;
    const int ch = hq * 256 + tid;          // x / z / g channel

    __shared__ float Bsh[16][68];           // [t][state]
    __shared__ float Csh[16][68];
    __shared__ float Gsh[16][16];           // [t][s] = C_t . B_s
    __shared__ float Msh[4][256];           // per-wave mask [t*16+s]
    __shared__ float red4[16][4];           // [t][wave] partial sumsq

    // ---- phase 0: load x-part (bf16) for own channel, all 16 t ----
    float ld[16];
#pragma unroll
    for (int t = 0; t < 16; ++t)
        ld[t] = __bfloat162float(zb[(size_t)(t * 256 + n) * ZLD + 1024 + ch]);

    const float cw0 = conv_w[ch * 4 + 0], cw1 = conv_w[ch * 4 + 1],
                cw2 = conv_w[ch * 4 + 2], cw3 = conv_w[ch * 4 + 3];
    const float cb = conv_b[ch];
    float xs[16];
#pragma unroll
    for (int t = 0; t < 16; ++t) {
        float a = fmaf(ld[t], cw3, cb);
        if (t >= 1) a = fmaf(ld[t - 1], cw2, a);
        if (t >= 2) a = fmaf(ld[t - 2], cw1, a);
        if (t >= 3) a = fmaf(ld[t - 3], cw0, a);
        xs[t] = a / (1.f + __expf(-a));
    }

    // ---- conv B/C channels (cols 2048..2175) by threads 0..127 ----
    if (tid < 128) {
        const int cc = 1024 + tid;
        const float dw0 = conv_w[cc * 4 + 0], dw1 = conv_w[cc * 4 + 1],
                    dw2 = conv_w[cc * 4 + 2], dw3 = conv_w[cc * 4 + 3];
        const float db = conv_b[cc];
        float q0 = 0.f, q1 = 0.f, q2 = 0.f;
#pragma unroll
        for (int t = 0; t < 16; ++t) {
            const float cur =
                __bfloat162float(zb[(size_t)(t * 256 + n) * ZLD + 2048 + tid]);
            float a = fmaf(cur, dw3, db);
            a = fmaf(q2, dw2, a);
            a = fmaf(q1, dw1, a);
            a = fmaf(q0, dw0, a);
            const float val = a / (1.f + __expf(-a));
            if (tid < 64) Bsh[t][tid] = val; else Csh[t][tid - 64] = val;
            q0 = q1; q1 = q2; q2 = cur;
        }
    }

    // ---- per-head dt (softplus, fp32) + inclusive cumsum over t ----
    const float a_h = -__expf(A_log[h]);
    float dtv_l = 0.f;
    if (p < 16) {
        const float raw = dtf[(size_t)(p * 256 + n) * 16 + h] + dt_bias[h];
        dtv_l = (raw > 20.f) ? raw : log1pf(__expf(raw));
    }
    float cum_l = dtv_l;
#pragma unroll
    for (int off = 1; off < 16; off <<= 1) {
        const float tmp = __shfl_up(cum_l, off);
        if (p >= off) cum_l += tmp;
    }
    __syncthreads();   // Bsh/Csh ready

    // ---- G[t][s] = C_t . B_s (head-independent) ----
    {
        const int t = tid >> 4, s = tid & 15;
        float acc = 0.f;
#pragma unroll
        for (int k = 0; k < 64; ++k)
            acc = fmaf(Csh[t][k], Bsh[s][k], acc);
        Gsh[t][s] = acc;
    }
    __syncthreads();

    // ---- per-head mask M[t][s] = exp(a*(cum_t-cum_s)) * G * dt_s ----
    float dtv_all[16], cum_all[16];
#pragma unroll
    for (int t = 0; t < 16; ++t) {
        dtv_all[t] = __shfl(dtv_l, t);
        cum_all[t] = __shfl(cum_l, t);
    }
#pragma unroll
    for (int q = 0; q < 4; ++q) {
        const int idx = p * 4 + q;
        const int t = idx >> 4, s = idx & 15;
        float m = 0.f;
        if (s <= t)
            m = __expf(a_h * (cum_all[t] - cum_all[s])) * Gsh[t][s] * dtv_all[s];
        Msh[w][idx] = m;   // wave-private; no barrier needed
    }

    // issue z loads; latency hides under phase 4 compute
    float zl[16];
#pragma unroll
    for (int t = 0; t < 16; ++t)
        zl[t] = __bfloat162float(zb[(size_t)(t * 256 + n) * ZLD + ch]);

    // ---- Y = M . x + D*x, gate with silu(z) ----
    const float Dh = Dp[h];
    float g[16];
#pragma unroll
    for (int t = 0; t < 16; ++t) {
        float y = 0.f;
#pragma unroll
        for (int s = 0; s <= t; ++s)
            y = fmaf(Msh[w][t * 16 + s], xs[s], y);
        y = fmaf(Dh, xs[t], y);
        g[t] = y * (zl[t] / (1.f + __expf(-zl[t])));
    }

    // ---- partial sum of squares per (t, wave) + write g ----
#pragma unroll
    for (int t = 0; t < 16; ++t) {
        float ss = g[t] * g[t];
#pragma unroll
        for (int off = 32; off >= 1; off >>= 1) ss += __shfl_xor(ss, off);
        if (p == 0) red4[t][w] = ss;
        gb[(size_t)(t * 256 + n) * DINNER + ch] = __float2bfloat16(g[t]);
    }
    __syncthreads();
    if (tid < 16)
        part[(size_t)(tid * 256 + n) * 4 + hq] =
            red4[tid][0] + red4[tid][1] + red4[tid][2] + red4[tid][3];
}

// ---------------------------------------------------------------------------
extern "C" void kernel_launch(void* const* d_in, const int* in_sizes, int n_in,
                              void* d_out, int out_size, void* d_ws, size_t ws_size,
                              hipStream_t stream) {
    const float* hs         = (const float*)d_in[0];   // (1,512,16,16,16)
    const float* proj_in_w  = (const float*)d_in[1];   // (512,512)
    const float* proj_in_b  = (const float*)d_in[2];   // (512)
    const float* proj_out_w = (const float*)d_in[3];   // (512,512)
    const float* proj_out_b = (const float*)d_in[4];   // (512)
    const float* in_proj_w  = (const float*)d_in[5];   // (2192,512)
    const float* conv_w     = (const float*)d_in[6];   // (1152,4)
    const float* conv_b     = (const float*)d_in[7];   // (1152)
    const float* dt_bias    = (const float*)d_in[8];   // (16)
    const float* A_log      = (const float*)d_in[9];   // (16)
    const float* Dp         = (const float*)d_in[10];  // (16)
    const float* norm_w     = (const float*)d_in[11];  // (1024)
    const float* out_proj_w = (const float*)d_in[12];  // (512,1024)
    float* out = (float*)d_out;

    // workspace layout (fp32 first, then bf16)
    float* ws      = (float*)d_ws;
    float* dtf     = ws;                                   // 4096*16 f32
    float* part    = dtf + (size_t)TOK * 16;               // 4096*4  f32
    float* Wc      = part + (size_t)TOK * 4;               // 16*512  f32
    float* bc      = Wc + 16 * DMODEL;                     // 16      f32
    float* zbias   = bc + 16;                              // 2176    f32
    bf16*  hsT     = (bf16*)(zbias + ZLD);                 // 4096*512
    bf16*  zb      = hsT + (size_t)TOK * DMODEL;           // 4096*2176
    bf16*  gb      = zb + (size_t)TOK * ZLD;               // 4096*1024
    bf16*  wpo     = gb + (size_t)TOK * DINNER;            // 512*512
    bf16*  wip     = wpo + SZ_PO;                          // 2176*512
    bf16*  wopT    = wip + SZ_IP2;                         // 1024*512 (nw folded)
    bf16*  wpiT    = wopT + (size_t)DINNER * DMODEL;       // 512*512 (pi^T)
    bf16*  Wfuse   = wpiT + (size_t)DMODEL * DMODEL;       // 2176*512
    bf16*  Wbig    = Wfuse + (size_t)ZLD * DMODEL;         // 512*1024

    // D1: Wc/bc/zbias (fp32), weights -> bf16, wpiT, wopT, hs -> hsT
    prep_all<<<NB_ALL, 256, 0, stream>>>(
        proj_in_w, proj_out_w, out_proj_w, in_proj_w, norm_w, proj_in_b, hs,
        wpo, wip, wpiT, wopT, hsT, Wc, bc, zbias);

    // D2: Wbig = wpo . wopT^T  and  Wfuse = wip . wpiT^T   (weights only)
    gemm_w<<<200, 256, 0, stream>>>(wpo, wopT, wip, wpiT, Wbig, Wfuse);

    // D3: zb = hsT . Wfuse^T + zbias (bf16)  and  dtf = hsT . Wc^T + bc (fp32)
    k2_dt<<<544 + TOK, 256, 0, stream>>>(
        hsT, Wfuse, zbias, Wc, bc, zb, dtf);

    // D4: fused conv + SSD + gate -> gb (bf16) + partial sumsq
    ssd_kernel<<<dim3(NSEQ, 4), 256, 0, stream>>>(
        zb, dtf, conv_w, conv_b, dt_bias, A_log, Dp, gb, part);

    // D5: out[c][v] = scale[v] * (Wbig[c][:] . gb[v][:]) + pob[c]
    k67_gemm<<<dim3(4, 64), 256, 0, stream>>>(
        Wbig, gb, proj_out_b, part, out, DINNER, DINNER, DINNER, TOK);
}